// Round 11
// baseline (1687.113 us; speedup 1.0000x reference)
//
#include <hip/hip_runtime.h>
#include <math.h>

#define HID 32
#define HOR 12
#define NB  256   // first-level blocks; k_binscan's 256 threads own one block each
#define GSH 8     // group shift: 256 nodes per group (392 write streams in scatter)
#define GW  256   // group width
#define NPT 4     // nodes per thread in k_gates general path

__device__ __forceinline__ float sigmoidf_(float x) { return 1.0f / (1.0f + expf(-x)); }

// ---------------------------------------------------------------------------
// Pipeline identical to round 9 except the k_gates fast path:
//   lane = node (64 nodes/block), wave = feature octet j0 = (wave id)*8.
//   Weights for gates {I,T,O} staged ONCE per block into LDS (24 KB);
//   k-loop reads them with wave-uniform ds_read_b128 (LDS broadcast, zero
//   bank conflicts), inputs are per-lane registers -> 48 pure v_fmac per
//   12 DS ops per k. No shuffles, no scalar-pipe weights (1-SGPR rule),
//   no per-k register tiles (round-9's VGPR bloat).
// ---------------------------------------------------------------------------

__global__ __launch_bounds__(1024) void k_hist(const int* __restrict__ src,
                                               const int* __restrict__ dst,
                                               int* __restrict__ hist,
                                               int E, int chunk, int ng) {
    __shared__ int hS[GW], hD[GW];
    int t = threadIdx.x, b = blockIdx.x;
    for (int i = t; i < ng; i += 1024) { hS[i] = 0; hD[i] = 0; }
    __syncthreads();
    int beg = b * chunk, end = min(E, beg + chunk);
    for (int e = beg + t; e < end; e += 1024) {
        atomicAdd(&hS[src[e] >> GSH], 1);
        atomicAdd(&hD[dst[e] >> GSH], 1);
    }
    __syncthreads();
    for (int i = t; i < ng; i += 1024) {
        hist[(size_t)i * NB + b] = hS[i];               // S bins: [0, ng)
        hist[((size_t)ng + i) * NB + b] = hD[i];        // D bins: [ng, 2ng)
    }
}

// per-bin exclusive scan across the NB blocks (one block per bin)
__global__ __launch_bounds__(256) void k_binscan(const int* __restrict__ hist,
                                                 int* __restrict__ off,
                                                 int* __restrict__ binTot, int ng2) {
    __shared__ int s[256];
    int b2 = blockIdx.x, t = threadIdx.x;
    int v = hist[(size_t)b2 * NB + t];                  // coalesced
    s[t] = v;
    __syncthreads();
    for (int o = 1; o < 256; o <<= 1) {
        int x = (t >= o) ? s[t - o] : 0;
        __syncthreads();
        s[t] += x;
        __syncthreads();
    }
    off[(size_t)t * ng2 + b2] = s[t] - v;               // block-major (scattered)
    if (t == 255) binTot[b2] = s[255];
}

// 2 blocks x 1024: block 0 scans S bin totals, block 1 scans D bin totals.
__global__ __launch_bounds__(1024) void k_binbase(const int* __restrict__ binTot,
                                                  int* __restrict__ baseS, int* __restrict__ baseD,
                                                  int* __restrict__ rowptr,
                                                  int E, int ng, int N) {
    __shared__ int buf[1024];
    int t = threadIdx.x;
    int isD = blockIdx.x;
    int sum = (t < ng) ? binTot[isD * ng + t] : 0;
    buf[t] = sum;
    __syncthreads();
    for (int o = 1; o < 1024; o <<= 1) {
        int v = (t >= o) ? buf[t - o] : 0;
        __syncthreads();
        buf[t] += v;
        __syncthreads();
    }
    int base = buf[t] - sum;                            // exclusive
    int* B = isD ? baseD : baseS;
    if (t < ng) B[t] = base;
    if (t == 0) { B[ng] = E; if (!isD) rowptr[N] = E; }
}

// per-edge scatter into 256-wide groups (both keyings) using LDS cursors.
__global__ __launch_bounds__(1024) void k_scatter(const int* __restrict__ src,
                                                  const int* __restrict__ dst,
                                                  const float* __restrict__ w,
                                                  const int* __restrict__ off,
                                                  const int* __restrict__ baseS,
                                                  const int* __restrict__ baseD,
                                                  int2* __restrict__ tmpS, int2* __restrict__ tmpD,
                                                  int E, int chunk, int ng) {
    __shared__ int cS[GW], cD[GW];
    int t = threadIdx.x, b = blockIdx.x;
    int ng2 = 2 * ng;
    for (int i = t; i < ng; i += 1024) {
        cS[i] = off[(size_t)b * ng2 + i] + baseS[i];          // coalesced
        cD[i] = off[(size_t)b * ng2 + ng + i] + baseD[i];
    }
    __syncthreads();
    int beg = b * chunk, end = min(E, beg + chunk);
    for (int e = beg + t; e < end; e += 1024) {
        int s = src[e], d = dst[e];
        int wb = __float_as_int(w[e]);
        int pS = atomicAdd(&cS[s >> GSH], 1);
        tmpS[pS] = make_int2(s, wb);
        int pD = atomicAdd(&cD[d >> GSH], 1);
        tmpD[pD] = make_int2(s | ((d & (GW - 1)) << 16), wb); // src fits 16 bits
    }
}

// per src-group: LDS float histogram over low 8 bits -> dinv (no global atomics)
__global__ __launch_bounds__(256) void k_degsum(const int2* __restrict__ tmpS,
                                                const int* __restrict__ baseS,
                                                float* __restrict__ dinv, int N) {
    __shared__ float h[GW];
    int g = blockIdx.x, t = threadIdx.x;
    h[t] = 0.0f;
    __syncthreads();
    int beg = baseS[g], end = baseS[g + 1];
    for (int i = beg + t; i < end; i += 256) {
        int2 p = tmpS[i];
        atomicAdd(&h[p.x & (GW - 1)], __int_as_float(p.y));
    }
    __syncthreads();
    int n = (g << GSH) + t;
    if (n < N) { float s = h[t]; dinv[n] = (s > 0.0f) ? rsqrtf(s) : 0.0f; }
}

// per dst-group: low-bits count + scan -> rowptr; then bin edges to exact dst,
// computing nw now that dinv exists. Within-dst order is arbitrary (sum).
__global__ __launch_bounds__(256) void k_scatter2(const int2* __restrict__ tmpD,
                                                  const int* __restrict__ baseD,
                                                  const float* __restrict__ dinv,
                                                  int* __restrict__ rowptr,
                                                  int2* __restrict__ epair, int N) {
    __shared__ int h[GW], cur[GW];
    int g = blockIdx.x, t = threadIdx.x;
    h[t] = 0;
    __syncthreads();
    int beg = baseD[g], end = baseD[g + 1];
    for (int i = beg + t; i < end; i += 256) atomicAdd(&h[(tmpD[i].x >> 16) & (GW - 1)], 1);
    __syncthreads();
    int v = h[t];
    for (int o = 1; o < GW; o <<= 1) {
        int x = (t >= o) ? h[t - o] : 0;
        __syncthreads();
        h[t] += x;
        __syncthreads();
    }
    int excl = h[t] - v;
    int n = (g << GSH) + t;
    if (n < N) rowptr[n] = beg + excl;
    cur[t] = beg + excl;
    __syncthreads();
    for (int i = beg + t; i < end; i += 256) {
        int2 p = tmpD[i];
        int low = (p.x >> 16) & (GW - 1);
        int s = p.x & 0xFFFF;
        int pos = atomicAdd(&cur[low], 1);
        float nw = -dinv[s] * __int_as_float(p.y) * dinv[(g << GSH) + low];
        epair[pos] = make_int2(s, __float_as_int(nw));
    }
}

// flag bit0 = any h0 nonzero, bit1 = any c0 nonzero
__global__ void k_flags(const float* __restrict__ h0, const float* __restrict__ c0,
                        int* __restrict__ flag, int total) {
    int i = blockIdx.x * 256 + threadIdx.x;
    float a = (i < total) ? h0[i] : 0.0f;
    float c = (i < total) ? c0[i] : 0.0f;
    unsigned long long ba = __ballot(a != 0.0f);
    unsigned long long bc = __ballot(c != 0.0f);
    if ((threadIdx.x & 63) == 0) {
        int m = (ba ? 1 : 0) | (bc ? 2 : 0);
        if (m) atomicOr(flag, m);
    }
}

// per dst node (32 lanes = 32 feats): accumulate LX (and LH if h0 nonzero)
__global__ __launch_bounds__(256) void k_gather(const int* __restrict__ rowptr,
                                                const int2* __restrict__ epair,
                                                const float* __restrict__ X,
                                                const float* __restrict__ H0,
                                                const int* __restrict__ hflag,
                                                float* __restrict__ LX, float* __restrict__ LH,
                                                int N) {
    int tid = blockIdx.x * 256 + threadIdx.x;
    int n = tid >> 5;
    int f = tid & 31;
    if (n >= N) return;
    int beg = rowptr[n], end = rowptr[n + 1];
    float acc = 0.0f, accH = 0.0f;
    int fl = *hflag;
    if (fl & 1) {
        #pragma unroll 4
        for (int i = beg; i < end; ++i) {
            int2 p = epair[i];
            float w = __int_as_float(p.y);
            acc  += w * X[(p.x << 5) + f];
            accH += w * H0[(p.x << 5) + f];
        }
    } else {
        #pragma unroll 4
        for (int i = beg; i < end; ++i) {
            int2 p = epair[i];
            acc += __int_as_float(p.y) * X[(p.x << 5) + f];
        }
    }
    LX[(n << 5) + f] = acc;
    if (fl & 1) LH[(n << 5) + f] = accH;   // LH is logically 0 otherwise; never read then
}

// Fast path: lane = node, LDS-staged weights read with wave-uniform b128.
// General path: proven round-8 shfl form (correctness-only; never hot here).
__global__ __launch_bounds__(256) void k_gates(
    const float* __restrict__ X, const float* __restrict__ LX,
    const float* __restrict__ H0, const float* __restrict__ LH,
    const float* __restrict__ C0,
    const float* __restrict__ Wx, const float* __restrict__ bx,
    const float* __restrict__ Wh, const float* __restrict__ bh,
    const float* __restrict__ wc, const float* __restrict__ b,
    const float* __restrict__ Wl, const float* __restrict__ bl,
    const int* __restrict__ flag,
    float* __restrict__ hOut, float* __restrict__ outH, float* __restrict__ outC,
    int N) {
    __shared__ float Wlds[32 * 3 * 2 * 32];   // [k][gate3][half][col], 24 KB
    __shared__ float Hl[HID][64];             // transposed relu(H) tile, 8 KB
    int f2 = *flag;

    if (f2 == 0) {
        // ---- fast path: h0 == 0 and c0 == 0 ----
        int fastB = (N + 63) >> 6;
        if (blockIdx.x >= fastB) return;
        int t = threadIdx.x;

        // stage gate weights {I(0),T(2),O(3)} x {X,LX} into LDS, coalesced
        for (int i = t; i < 6144; i += 256) {
            int col = i & 31;
            int h = (i >> 5) & 1;
            int rem = i >> 6;
            int g = rem % 3;                   // 0->gate0, 1->gate2, 2->gate3
            int k = rem / 3;
            int g4 = (g == 0) ? 0 : (g + 1);   // 0,2,3
            Wlds[i] = Wx[g4 * 2048 + h * 1024 + k * 32 + col];
        }
        __syncthreads();

        int ln = t & 63;                                   // node within block
        int n = (blockIdx.x << 6) + ln;
        int jc = __builtin_amdgcn_readfirstlane(t >> 6);   // wave id 0..3 (uniform)
        int j0 = jc << 3;                                  // feature octet base

        if (n < N) {
            // per-lane input rows in registers (static-indexed -> VGPRs)
            const float4* Xr = (const float4*)(X + ((size_t)n << 5));
            const float4* Lr = (const float4*)(LX + ((size_t)n << 5));
            float4 x4[8], l4[8];
            #pragma unroll
            for (int q = 0; q < 8; ++q) { x4[q] = Xr[q]; l4[q] = Lr[q]; }

            float aI[8], aT[8], aO[8];
            #pragma unroll
            for (int jj = 0; jj < 8; ++jj) {
                aI[jj] = bx[j0 + jj]         + bh[j0 + jj]         + b[j0 + jj];
                aT[jj] = bx[2*HID + j0 + jj] + bh[2*HID + j0 + jj] + b[2*HID + j0 + jj];
                aO[jj] = bx[3*HID + j0 + jj] + bh[3*HID + j0 + jj] + b[3*HID + j0 + jj];
            }

            #pragma unroll
            for (int q = 0; q < 8; ++q) {
                #pragma unroll
                for (int dk = 0; dk < 4; ++dk) {
                    int k = 4 * q + dk;
                    float xv = (dk == 0) ? x4[q].x : (dk == 1) ? x4[q].y : (dk == 2) ? x4[q].z : x4[q].w;
                    float lv = (dk == 0) ? l4[q].x : (dk == 1) ? l4[q].y : (dk == 2) ? l4[q].z : l4[q].w;
                    int kb = k * 192;                      // k*3*2*32
                    // wave-uniform addresses -> ds_read_b128 broadcasts
                    const float4* wI0 = (const float4*)&Wlds[kb + j0];            // gate I, X half
                    const float4* wI1 = (const float4*)&Wlds[kb + 32 + j0];       // gate I, LX half
                    const float4* wT0 = (const float4*)&Wlds[kb + 64 + j0];
                    const float4* wT1 = (const float4*)&Wlds[kb + 96 + j0];
                    const float4* wO0 = (const float4*)&Wlds[kb + 128 + j0];
                    const float4* wO1 = (const float4*)&Wlds[kb + 160 + j0];
                    float4 i0a = wI0[0], i0b = wI0[1], i1a = wI1[0], i1b = wI1[1];
                    float4 t0a = wT0[0], t0b = wT0[1], t1a = wT1[0], t1b = wT1[1];
                    float4 o0a = wO0[0], o0b = wO0[1], o1a = wO1[0], o1b = wO1[1];
                    aI[0] += xv * i0a.x + lv * i1a.x;  aI[1] += xv * i0a.y + lv * i1a.y;
                    aI[2] += xv * i0a.z + lv * i1a.z;  aI[3] += xv * i0a.w + lv * i1a.w;
                    aI[4] += xv * i0b.x + lv * i1b.x;  aI[5] += xv * i0b.y + lv * i1b.y;
                    aI[6] += xv * i0b.z + lv * i1b.z;  aI[7] += xv * i0b.w + lv * i1b.w;
                    aT[0] += xv * t0a.x + lv * t1a.x;  aT[1] += xv * t0a.y + lv * t1a.y;
                    aT[2] += xv * t0a.z + lv * t1a.z;  aT[3] += xv * t0a.w + lv * t1a.w;
                    aT[4] += xv * t0b.x + lv * t1b.x;  aT[5] += xv * t0b.y + lv * t1b.y;
                    aT[6] += xv * t0b.z + lv * t1b.z;  aT[7] += xv * t0b.w + lv * t1b.w;
                    aO[0] += xv * o0a.x + lv * o1a.x;  aO[1] += xv * o0a.y + lv * o1a.y;
                    aO[2] += xv * o0a.z + lv * o1a.z;  aO[3] += xv * o0a.w + lv * o1a.w;
                    aO[4] += xv * o0b.x + lv * o1b.x;  aO[5] += xv * o0b.y + lv * o1b.y;
                    aO[6] += xv * o0b.z + lv * o1b.z;  aO[7] += xv * o0b.w + lv * o1b.w;
                }
            }

            float h8[8], c8[8];
            #pragma unroll
            for (int jj = 0; jj < 8; ++jj) {
                float I = sigmoidf_(aI[jj]);
                float T = tanhf(aT[jj]);
                float C = I * T;
                float O = sigmoidf_(aO[jj] + wc[2*HID + j0 + jj] * C);
                float H = O * tanhf(C);
                h8[jj] = H;
                c8[jj] = C;
                Hl[j0 + jj][ln] = fmaxf(H, 0.0f);      // transposed, conflict-free
            }
            size_t base = ((size_t)n << 5) + j0;
            *(float4*)(outH + base)     = make_float4(h8[0], h8[1], h8[2], h8[3]);
            *(float4*)(outH + base + 4) = make_float4(h8[4], h8[5], h8[6], h8[7]);
            *(float4*)(outC + base)     = make_float4(c8[0], c8[1], c8[2], c8[3]);
            *(float4*)(outC + base + 4) = make_float4(c8[4], c8[5], c8[6], c8[7]);
        }
        __syncthreads();

        // head: thread -> (node = t&63, 3 horizons); Wl loads wave-uniform
        int hn = t & 63;
        int hw = __builtin_amdgcn_readfirstlane(t >> 6);
        int n2 = (blockIdx.x << 6) + hn;
        if (n2 < N) {
            int jb = hw * 3;
            float a0 = bl[jb], a1 = bl[jb + 1], a2 = bl[jb + 2];
            #pragma unroll
            for (int k = 0; k < HID; ++k) {
                float hv = Hl[k][hn];                  // consecutive lanes, conflict-free
                a0 += hv * Wl[k * HOR + jb];
                a1 += hv * Wl[k * HOR + jb + 1];
                a2 += hv * Wl[k * HOR + jb + 2];
            }
            size_t ob = (size_t)n2 * HOR + jb;
            hOut[ob] = a0; hOut[ob + 1] = a1; hOut[ob + 2] = a2;
        }
        return;
    }

    // ---- general path (shfl form; correctness-only) ----
    int tid = blockIdx.x * 256 + threadIdx.x;
    int g = tid >> 5;
    int j = tid & 31;
    int n0 = g * NPT;
    if (n0 >= N) return;
    int cnt = min(NPT, N - n0);
    float blv = (j < HOR) ? bl[j] : 0.0f;

    float xk[NPT], lxk[NPT], hk[NPT], lhk[NPT];
    #pragma unroll
    for (int i = 0; i < NPT; ++i) { xk[i] = 0.0f; lxk[i] = 0.0f; hk[i] = 0.0f; lhk[i] = 0.0f; }
    for (int i = 0; i < cnt; ++i) {
        int base = (n0 + i) << 5;
        xk[i]  = X[base + j];
        lxk[i] = LX[base + j];
        hk[i]  = H0[base + j];
        lhk[i] = (f2 & 1) ? LH[base + j] : 0.0f;   // LH only valid if h0 nonzero
    }

    float pre[4][NPT];
    #pragma unroll
    for (int gt = 0; gt < 4; ++gt) {
        float bb = bx[gt * HID + j] + bh[gt * HID + j] + b[gt * HID + j];
        #pragma unroll
        for (int i = 0; i < NPT; ++i) pre[gt][i] = bb;
    }

    #pragma unroll 2
    for (int k = 0; k < HID; ++k) {
        float w0[4], w1[4], w2[4], w3[4];
        int row = k * HID + j;
        #pragma unroll
        for (int gt = 0; gt < 4; ++gt) {
            w0[gt] = Wx[gt * 2048 + row];
            w1[gt] = Wx[gt * 2048 + 1024 + row];
            w2[gt] = Wh[gt * 2048 + row];
            w3[gt] = Wh[gt * 2048 + 1024 + row];
        }
        #pragma unroll
        for (int i = 0; i < NPT; ++i) {
            float xv  = __shfl(xk[i],  k, 32);
            float lxv = __shfl(lxk[i], k, 32);
            float hv  = __shfl(hk[i],  k, 32);
            float lhv = __shfl(lhk[i], k, 32);
            #pragma unroll
            for (int gt = 0; gt < 4; ++gt)
                pre[gt][i] += xv * w0[gt] + lxv * w1[gt] + hv * w2[gt] + lhv * w3[gt];
        }
    }

    float wc0 = wc[0 * HID + j], wc1 = wc[1 * HID + j], wc2 = wc[2 * HID + j];
    for (int i = 0; i < cnt; ++i) {
        int n = n0 + i;
        int base = n << 5;
        float c0v = C0[base + j];
        float I  = sigmoidf_(pre[0][i] + wc0 * c0v);
        float Fg = sigmoidf_(pre[1][i] + wc1 * c0v);
        float T  = tanhf(pre[2][i]);
        float C  = Fg * c0v + I * T;
        float O  = sigmoidf_(pre[3][i] + wc2 * C);
        float H  = O * tanhf(C);
        outH[base + j] = H;
        outC[base + j] = C;
        float ah = blv;
        #pragma unroll 8
        for (int k = 0; k < HID; ++k) {
            float hv = __shfl(H, k, 32);
            if (j < HOR) ah += fmaxf(hv, 0.0f) * Wl[k * HOR + j];
        }
        if (j < HOR) hOut[(size_t)n * HOR + j] = ah;
    }
}

extern "C" void kernel_launch(void* const* d_in, const int* in_sizes, int n_in,
                              void* d_out, int out_size, void* d_ws, size_t ws_size,
                              hipStream_t stream) {
    const float* x  = (const float*)d_in[0];
    const int*   ei = (const int*)d_in[1];
    const float* ew = (const float*)d_in[2];
    const float* Wx = (const float*)d_in[3];
    const float* bx = (const float*)d_in[4];
    const float* Wh = (const float*)d_in[5];
    const float* bh = (const float*)d_in[6];
    const float* wc = (const float*)d_in[7];
    const float* b  = (const float*)d_in[8];
    const float* Wl = (const float*)d_in[9];
    const float* bl = (const float*)d_in[10];
    const float* h0 = (const float*)d_in[11];
    const float* c0 = (const float*)d_in[12];

    int N = in_sizes[0] / HID;      // x is (N,1,32)
    int E = in_sizes[2];            // edge_weight is (E,)
    const int* src = ei;
    const int* dst = ei + E;

    int ng = (N + GW - 1) >> GSH;   // 196 groups (requires N <= 65536)
    int ng2 = 2 * ng;
    int chunk = (E + NB - 1) / NB;  // edges per hist/scatter block

    // workspace (4-byte units):
    // [tmpD 2E] [tmpS 2E (aliased by epair)] [LX N*32] [LH N*32] [rowptr N+1]
    // [hist ng2*NB] [off ng2*NB] [binTot 2048] [baseS ng+1] [baseD ng+1] [dinv N] [flag 1]
    // tmpS is dead after k_degsum, so k_scatter2 may overwrite it with epair.
    int* wsi = (int*)d_ws;
    int2*  tmpD   = (int2*)wsi;
    int2*  tmpS   = (int2*)(wsi + 2 * (size_t)E);
    int2*  epair  = tmpS;                                // alias (see above)
    float* LX     = (float*)(wsi + 4 * (size_t)E);
    float* LH     = LX + (size_t)N * HID;
    int*   rowptr = (int*)(LH + (size_t)N * HID);
    int*   hist   = rowptr + (N + 1);
    int*   off    = hist + (size_t)ng2 * NB;
    int*   binTot = off + (size_t)ng2 * NB;
    int*   baseS  = binTot + 2048;
    int*   baseD  = baseS + (ng + 1);
    float* dinv   = (float*)(baseD + (ng + 1));
    int*   flag   = (int*)(dinv + N);

    float* hOut = (float*)d_out;            // (N,12)
    float* HOut = hOut + (size_t)N * HOR;   // (N,32)
    float* COut = HOut + (size_t)N * HID;   // (N,32)

    hipMemsetAsync(flag, 0, sizeof(int), stream);

    k_hist<<<NB, 1024, 0, stream>>>(src, dst, hist, E, chunk, ng);
    k_binscan<<<ng2, 256, 0, stream>>>(hist, off, binTot, ng2);
    k_binbase<<<2, 1024, 0, stream>>>(binTot, baseS, baseD, rowptr, E, ng, N);
    k_scatter<<<NB, 1024, 0, stream>>>(src, dst, ew, off, baseS, baseD, tmpS, tmpD, E, chunk, ng);
    k_degsum<<<ng, 256, 0, stream>>>(tmpS, baseS, dinv, N);
    k_flags<<<(N * HID + 255) / 256, 256, 0, stream>>>(h0, c0, flag, N * HID);
    k_scatter2<<<ng, 256, 0, stream>>>(tmpD, baseD, dinv, rowptr, epair, N);

    k_gather<<<(N * HID + 255) / 256, 256, 0, stream>>>(rowptr, epair, x, h0, flag, LX, LH, N);

    int gThreads = ((N + NPT - 1) / NPT) * 32;
    k_gates<<<(gThreads + 255) / 256, 256, 0, stream>>>(x, LX, h0, LH, c0,
                                                        Wx, bx, Wh, bh, wc, b, Wl, bl, flag,
                                                        hOut, HOut, COut, N);
}

// Round 12
// 252.617 us; speedup vs baseline: 6.6785x; 6.6785x over previous
//
#include <hip/hip_runtime.h>
#include <math.h>

#define HID 32
#define HOR 12
#define NB  256   // first-level blocks; k_binscan's 256 threads own one block each
#define GSH 8     // group shift: 256 nodes per group (392 write streams in scatter)
#define GW  256   // group width
#define NPT 4     // nodes per thread in k_gates

__device__ __forceinline__ float sigmoidf_(float x) { return 1.0f / (1.0f + expf(-x)); }

// ---------------------------------------------------------------------------
// Recovery round: round-9 champion pipeline (272.3 us) verbatim, with k_gates
// restored to the measured-good NPT=4 shfl form (round 4/5, <=50 us) and the
// head DE-fused back into its own tiny kernel (round 2 form, ~8 us). The
// fused head cost ~15-20 us of low-utilization shfl inside gates (r8: 65 us
// fused vs ~45+8 unfused). No other changes.
// ---------------------------------------------------------------------------

__global__ __launch_bounds__(1024) void k_hist(const int* __restrict__ src,
                                               const int* __restrict__ dst,
                                               int* __restrict__ hist,
                                               int E, int chunk, int ng) {
    __shared__ int hS[GW], hD[GW];
    int t = threadIdx.x, b = blockIdx.x;
    for (int i = t; i < ng; i += 1024) { hS[i] = 0; hD[i] = 0; }
    __syncthreads();
    int beg = b * chunk, end = min(E, beg + chunk);
    for (int e = beg + t; e < end; e += 1024) {
        atomicAdd(&hS[src[e] >> GSH], 1);
        atomicAdd(&hD[dst[e] >> GSH], 1);
    }
    __syncthreads();
    for (int i = t; i < ng; i += 1024) {
        hist[(size_t)i * NB + b] = hS[i];               // S bins: [0, ng)
        hist[((size_t)ng + i) * NB + b] = hD[i];        // D bins: [ng, 2ng)
    }
}

// per-bin exclusive scan across the NB blocks (one block per bin)
__global__ __launch_bounds__(256) void k_binscan(const int* __restrict__ hist,
                                                 int* __restrict__ off,
                                                 int* __restrict__ binTot, int ng2) {
    __shared__ int s[256];
    int b2 = blockIdx.x, t = threadIdx.x;
    int v = hist[(size_t)b2 * NB + t];                  // coalesced
    s[t] = v;
    __syncthreads();
    for (int o = 1; o < 256; o <<= 1) {
        int x = (t >= o) ? s[t - o] : 0;
        __syncthreads();
        s[t] += x;
        __syncthreads();
    }
    off[(size_t)t * ng2 + b2] = s[t] - v;               // block-major (scattered)
    if (t == 255) binTot[b2] = s[255];
}

// 2 blocks x 1024: block 0 scans S bin totals, block 1 scans D bin totals.
__global__ __launch_bounds__(1024) void k_binbase(const int* __restrict__ binTot,
                                                  int* __restrict__ baseS, int* __restrict__ baseD,
                                                  int* __restrict__ rowptr,
                                                  int E, int ng, int N) {
    __shared__ int buf[1024];
    int t = threadIdx.x;
    int isD = blockIdx.x;
    int sum = (t < ng) ? binTot[isD * ng + t] : 0;
    buf[t] = sum;
    __syncthreads();
    for (int o = 1; o < 1024; o <<= 1) {
        int v = (t >= o) ? buf[t - o] : 0;
        __syncthreads();
        buf[t] += v;
        __syncthreads();
    }
    int base = buf[t] - sum;                            // exclusive
    int* B = isD ? baseD : baseS;
    if (t < ng) B[t] = base;
    if (t == 0) { B[ng] = E; if (!isD) rowptr[N] = E; }
}

// per-edge scatter into 256-wide groups (both keyings) using LDS cursors.
__global__ __launch_bounds__(1024) void k_scatter(const int* __restrict__ src,
                                                  const int* __restrict__ dst,
                                                  const float* __restrict__ w,
                                                  const int* __restrict__ off,
                                                  const int* __restrict__ baseS,
                                                  const int* __restrict__ baseD,
                                                  int2* __restrict__ tmpS, int2* __restrict__ tmpD,
                                                  int E, int chunk, int ng) {
    __shared__ int cS[GW], cD[GW];
    int t = threadIdx.x, b = blockIdx.x;
    int ng2 = 2 * ng;
    for (int i = t; i < ng; i += 1024) {
        cS[i] = off[(size_t)b * ng2 + i] + baseS[i];          // coalesced
        cD[i] = off[(size_t)b * ng2 + ng + i] + baseD[i];
    }
    __syncthreads();
    int beg = b * chunk, end = min(E, beg + chunk);
    for (int e = beg + t; e < end; e += 1024) {
        int s = src[e], d = dst[e];
        int wb = __float_as_int(w[e]);
        int pS = atomicAdd(&cS[s >> GSH], 1);
        tmpS[pS] = make_int2(s, wb);
        int pD = atomicAdd(&cD[d >> GSH], 1);
        tmpD[pD] = make_int2(s | ((d & (GW - 1)) << 16), wb); // src fits 16 bits
    }
}

// per src-group: LDS float histogram over low 8 bits -> dinv (no global atomics)
__global__ __launch_bounds__(256) void k_degsum(const int2* __restrict__ tmpS,
                                                const int* __restrict__ baseS,
                                                float* __restrict__ dinv, int N) {
    __shared__ float h[GW];
    int g = blockIdx.x, t = threadIdx.x;
    h[t] = 0.0f;
    __syncthreads();
    int beg = baseS[g], end = baseS[g + 1];
    for (int i = beg + t; i < end; i += 256) {
        int2 p = tmpS[i];
        atomicAdd(&h[p.x & (GW - 1)], __int_as_float(p.y));
    }
    __syncthreads();
    int n = (g << GSH) + t;
    if (n < N) { float s = h[t]; dinv[n] = (s > 0.0f) ? rsqrtf(s) : 0.0f; }
}

// per dst-group: low-bits count + scan -> rowptr; then bin edges to exact dst,
// computing nw now that dinv exists. Within-dst order is arbitrary (sum).
__global__ __launch_bounds__(256) void k_scatter2(const int2* __restrict__ tmpD,
                                                  const int* __restrict__ baseD,
                                                  const float* __restrict__ dinv,
                                                  int* __restrict__ rowptr,
                                                  int2* __restrict__ epair, int N) {
    __shared__ int h[GW], cur[GW];
    int g = blockIdx.x, t = threadIdx.x;
    h[t] = 0;
    __syncthreads();
    int beg = baseD[g], end = baseD[g + 1];
    for (int i = beg + t; i < end; i += 256) atomicAdd(&h[(tmpD[i].x >> 16) & (GW - 1)], 1);
    __syncthreads();
    int v = h[t];
    for (int o = 1; o < GW; o <<= 1) {
        int x = (t >= o) ? h[t - o] : 0;
        __syncthreads();
        h[t] += x;
        __syncthreads();
    }
    int excl = h[t] - v;
    int n = (g << GSH) + t;
    if (n < N) rowptr[n] = beg + excl;
    cur[t] = beg + excl;
    __syncthreads();
    for (int i = beg + t; i < end; i += 256) {
        int2 p = tmpD[i];
        int low = (p.x >> 16) & (GW - 1);
        int s = p.x & 0xFFFF;
        int pos = atomicAdd(&cur[low], 1);
        float nw = -dinv[s] * __int_as_float(p.y) * dinv[(g << GSH) + low];
        epair[pos] = make_int2(s, __float_as_int(nw));
    }
}

// flag bit0 = any h0 nonzero, bit1 = any c0 nonzero
__global__ void k_flags(const float* __restrict__ h0, const float* __restrict__ c0,
                        int* __restrict__ flag, int total) {
    int i = blockIdx.x * 256 + threadIdx.x;
    float a = (i < total) ? h0[i] : 0.0f;
    float c = (i < total) ? c0[i] : 0.0f;
    unsigned long long ba = __ballot(a != 0.0f);
    unsigned long long bc = __ballot(c != 0.0f);
    if ((threadIdx.x & 63) == 0) {
        int m = (ba ? 1 : 0) | (bc ? 2 : 0);
        if (m) atomicOr(flag, m);
    }
}

// per dst node (32 lanes = 32 feats): accumulate LX (and LH if h0 nonzero)
__global__ __launch_bounds__(256) void k_gather(const int* __restrict__ rowptr,
                                                const int2* __restrict__ epair,
                                                const float* __restrict__ X,
                                                const float* __restrict__ H0,
                                                const int* __restrict__ hflag,
                                                float* __restrict__ LX, float* __restrict__ LH,
                                                int N) {
    int tid = blockIdx.x * 256 + threadIdx.x;
    int n = tid >> 5;
    int f = tid & 31;
    if (n >= N) return;
    int beg = rowptr[n], end = rowptr[n + 1];
    float acc = 0.0f, accH = 0.0f;
    int fl = *hflag;
    if (fl & 1) {
        #pragma unroll 4
        for (int i = beg; i < end; ++i) {
            int2 p = epair[i];
            float w = __int_as_float(p.y);
            acc  += w * X[(p.x << 5) + f];
            accH += w * H0[(p.x << 5) + f];
        }
    } else {
        #pragma unroll 4
        for (int i = beg; i < end; ++i) {
            int2 p = epair[i];
            acc += __int_as_float(p.y) * X[(p.x << 5) + f];
        }
    }
    LX[(n << 5) + f] = acc;
    if (fl & 1) LH[(n << 5) + f] = accH;   // LH is logically 0 otherwise; never read then
}

// Per (node-group g of NPT nodes, out-feature j): fused LSTM cell (no head).
// Fast path (h0==0 && c0==0, detected at runtime): F-gate dead (C = I*T),
// h/lh terms are exact zero-adds -> 3 gates x 2 input types. Bit-identical.
__global__ __launch_bounds__(256) void k_gates(
    const float* __restrict__ X, const float* __restrict__ LX,
    const float* __restrict__ H0, const float* __restrict__ LH,
    const float* __restrict__ C0,
    const float* __restrict__ Wx, const float* __restrict__ bx,
    const float* __restrict__ Wh, const float* __restrict__ bh,
    const float* __restrict__ wc, const float* __restrict__ b,
    const int* __restrict__ flag,
    float* __restrict__ outH, float* __restrict__ outC, int N) {
    int tid = blockIdx.x * 256 + threadIdx.x;
    int g = tid >> 5;           // node group
    int j = tid & 31;           // output feature
    int n0 = g * NPT;
    if (n0 >= N) return;
    int cnt = min(NPT, N - n0);
    int f2 = *flag;

    if (f2 == 0) {
        // ---- fast path: h0 == 0 and c0 == 0 ----
        float xk[NPT], lxk[NPT];
        #pragma unroll
        for (int i = 0; i < NPT; ++i) { xk[i] = 0.0f; lxk[i] = 0.0f; }
        for (int i = 0; i < cnt; ++i) {
            int base = (n0 + i) << 5;
            xk[i]  = X[base + j];
            lxk[i] = LX[base + j];
        }
        float p0[NPT], p2[NPT], p3[NPT];
        float b0 = bx[0 * HID + j] + bh[0 * HID + j] + b[0 * HID + j];
        float b2 = bx[2 * HID + j] + bh[2 * HID + j] + b[2 * HID + j];
        float b3 = bx[3 * HID + j] + bh[3 * HID + j] + b[3 * HID + j];
        #pragma unroll
        for (int i = 0; i < NPT; ++i) { p0[i] = b0; p2[i] = b2; p3[i] = b3; }

        #pragma unroll 4
        for (int k = 0; k < HID; ++k) {
            int row = k * HID + j;
            float w00 = Wx[row],            w01 = Wx[1024 + row];
            float w20 = Wx[2 * 2048 + row], w21 = Wx[2 * 2048 + 1024 + row];
            float w30 = Wx[3 * 2048 + row], w31 = Wx[3 * 2048 + 1024 + row];
            #pragma unroll
            for (int i = 0; i < NPT; ++i) {
                float xv  = __shfl(xk[i],  k, 32);
                float lxv = __shfl(lxk[i], k, 32);
                p0[i] += xv * w00 + lxv * w01;
                p2[i] += xv * w20 + lxv * w21;
                p3[i] += xv * w30 + lxv * w31;
            }
        }

        float wc2 = wc[2 * HID + j];
        for (int i = 0; i < cnt; ++i) {
            int base = (n0 + i) << 5;
            float I = sigmoidf_(p0[i]);
            float T = tanhf(p2[i]);
            float C = I * T;
            float O = sigmoidf_(p3[i] + wc2 * C);
            outH[base + j] = O * tanhf(C);
            outC[base + j] = C;
        }
        return;
    }

    // ---- general path ----
    float xk[NPT], lxk[NPT], hk[NPT], lhk[NPT];
    #pragma unroll
    for (int i = 0; i < NPT; ++i) { xk[i] = 0.0f; lxk[i] = 0.0f; hk[i] = 0.0f; lhk[i] = 0.0f; }
    for (int i = 0; i < cnt; ++i) {
        int base = (n0 + i) << 5;
        xk[i]  = X[base + j];
        lxk[i] = LX[base + j];
        hk[i]  = H0[base + j];
        lhk[i] = (f2 & 1) ? LH[base + j] : 0.0f;   // LH only valid if h0 nonzero
    }

    float pre[4][NPT];
    #pragma unroll
    for (int gt = 0; gt < 4; ++gt) {
        float bb = bx[gt * HID + j] + bh[gt * HID + j] + b[gt * HID + j];
        #pragma unroll
        for (int i = 0; i < NPT; ++i) pre[gt][i] = bb;
    }

    #pragma unroll 2
    for (int k = 0; k < HID; ++k) {
        float w0[4], w1[4], w2[4], w3[4];
        int row = k * HID + j;
        #pragma unroll
        for (int gt = 0; gt < 4; ++gt) {
            w0[gt] = Wx[gt * 2048 + row];
            w1[gt] = Wx[gt * 2048 + 1024 + row];
            w2[gt] = Wh[gt * 2048 + row];
            w3[gt] = Wh[gt * 2048 + 1024 + row];
        }
        #pragma unroll
        for (int i = 0; i < NPT; ++i) {
            float xv  = __shfl(xk[i],  k, 32);
            float lxv = __shfl(lxk[i], k, 32);
            float hv  = __shfl(hk[i],  k, 32);
            float lhv = __shfl(lhk[i], k, 32);
            #pragma unroll
            for (int gt = 0; gt < 4; ++gt)
                pre[gt][i] += xv * w0[gt] + lxv * w1[gt] + hv * w2[gt] + lhv * w3[gt];
        }
    }

    float wc0 = wc[0 * HID + j], wc1 = wc[1 * HID + j], wc2 = wc[2 * HID + j];
    for (int i = 0; i < cnt; ++i) {
        int base = (n0 + i) << 5;
        float c0v = C0[base + j];
        float I  = sigmoidf_(pre[0][i] + wc0 * c0v);
        float Fg = sigmoidf_(pre[1][i] + wc1 * c0v);
        float T  = tanhf(pre[2][i]);
        float C  = Fg * c0v + I * T;
        float O  = sigmoidf_(pre[3][i] + wc2 * C);
        float H  = O * tanhf(C);
        outH[base + j] = H;
        outC[base + j] = C;
    }
}

// h[n,t] = b_lin[t] + sum_k relu(H[n,k]) * W_lin[k,t]
__global__ void k_head(const float* __restrict__ H, const float* __restrict__ Wl,
                       const float* __restrict__ bl, float* __restrict__ hout, int N) {
    int tid = blockIdx.x * 256 + threadIdx.x;
    int n = tid / HOR;
    int t = tid - n * HOR;
    if (n >= N) return;
    float acc = bl[t];
    #pragma unroll
    for (int k = 0; k < HID; ++k) {
        float v = H[(n << 5) + k];
        acc += fmaxf(v, 0.0f) * Wl[k * HOR + t];
    }
    hout[n * HOR + t] = acc;
}

extern "C" void kernel_launch(void* const* d_in, const int* in_sizes, int n_in,
                              void* d_out, int out_size, void* d_ws, size_t ws_size,
                              hipStream_t stream) {
    const float* x  = (const float*)d_in[0];
    const int*   ei = (const int*)d_in[1];
    const float* ew = (const float*)d_in[2];
    const float* Wx = (const float*)d_in[3];
    const float* bx = (const float*)d_in[4];
    const float* Wh = (const float*)d_in[5];
    const float* bh = (const float*)d_in[6];
    const float* wc = (const float*)d_in[7];
    const float* b  = (const float*)d_in[8];
    const float* Wl = (const float*)d_in[9];
    const float* bl = (const float*)d_in[10];
    const float* h0 = (const float*)d_in[11];
    const float* c0 = (const float*)d_in[12];

    int N = in_sizes[0] / HID;      // x is (N,1,32)
    int E = in_sizes[2];            // edge_weight is (E,)
    const int* src = ei;
    const int* dst = ei + E;

    int ng = (N + GW - 1) >> GSH;   // 196 groups (requires N <= 65536)
    int ng2 = 2 * ng;
    int chunk = (E + NB - 1) / NB;  // edges per hist/scatter block

    // workspace (4-byte units):
    // [tmpD 2E] [tmpS 2E (aliased by epair)] [LX N*32] [LH N*32] [rowptr N+1]
    // [hist ng2*NB] [off ng2*NB] [binTot 2048] [baseS ng+1] [baseD ng+1] [dinv N] [flag 1]
    // tmpS is dead after k_degsum, so k_scatter2 may overwrite it with epair.
    int* wsi = (int*)d_ws;
    int2*  tmpD   = (int2*)wsi;
    int2*  tmpS   = (int2*)(wsi + 2 * (size_t)E);
    int2*  epair  = tmpS;                                // alias (see above)
    float* LX     = (float*)(wsi + 4 * (size_t)E);
    float* LH     = LX + (size_t)N * HID;
    int*   rowptr = (int*)(LH + (size_t)N * HID);
    int*   hist   = rowptr + (N + 1);
    int*   off    = hist + (size_t)ng2 * NB;
    int*   binTot = off + (size_t)ng2 * NB;
    int*   baseS  = binTot + 2048;
    int*   baseD  = baseS + (ng + 1);
    float* dinv   = (float*)(baseD + (ng + 1));
    int*   flag   = (int*)(dinv + N);

    float* hOut = (float*)d_out;            // (N,12)
    float* HOut = hOut + (size_t)N * HOR;   // (N,32)
    float* COut = HOut + (size_t)N * HID;   // (N,32)

    hipMemsetAsync(flag, 0, sizeof(int), stream);

    k_hist<<<NB, 1024, 0, stream>>>(src, dst, hist, E, chunk, ng);
    k_binscan<<<ng2, 256, 0, stream>>>(hist, off, binTot, ng2);
    k_binbase<<<2, 1024, 0, stream>>>(binTot, baseS, baseD, rowptr, E, ng, N);
    k_scatter<<<NB, 1024, 0, stream>>>(src, dst, ew, off, baseS, baseD, tmpS, tmpD, E, chunk, ng);
    k_degsum<<<ng, 256, 0, stream>>>(tmpS, baseS, dinv, N);
    k_flags<<<(N * HID + 255) / 256, 256, 0, stream>>>(h0, c0, flag, N * HID);
    k_scatter2<<<ng, 256, 0, stream>>>(tmpD, baseD, dinv, rowptr, epair, N);

    k_gather<<<(N * HID + 255) / 256, 256, 0, stream>>>(rowptr, epair, x, h0, flag, LX, LH, N);

    int gThreads = ((N + NPT - 1) / NPT) * 32;
    k_gates<<<(gThreads + 255) / 256, 256, 0, stream>>>(x, LX, h0, LH, c0,
                                                        Wx, bx, Wh, bh, wc, b, flag,
                                                        HOut, COut, N);

    k_head<<<(N * HOR + 255) / 256, 256, 0, stream>>>(HOut, Wl, bl, hOut, N);
}

// Round 13
// 243.525 us; speedup vs baseline: 6.9279x; 1.0373x over previous
//
#include <hip/hip_runtime.h>
#include <math.h>

#define HID 32
#define HOR 12
#define NB  256   // first-level blocks; k_binscan's 256 threads own one block each
#define GSH 8     // group shift: 256 nodes per group (392 write streams in scatter)
#define GW  256   // group width
#define NPT 4     // nodes per thread in k_gates

__device__ __forceinline__ float sigmoidf_(float x) { return 1.0f / (1.0f + expf(-x)); }

// ---------------------------------------------------------------------------
// Round-12 champion (252.6 us) with two occupancy/launch fixes:
//  - k_degsum / k_scatter2 now run 1024 threads/block (16 waves per occupied
//    CU instead of 4; they were the most starved kernels in the chain).
//  - k_flags folded into k_hist (one less launch; hist already streams 12.8MB,
//    the extra h0/c0 scan is ~2us of bandwidth on idle lanes).
// Everything else byte-identical to round 12.
// ---------------------------------------------------------------------------

// per-block histograms of src>>8 and dst>>8, written bin-major.
// Also computes flag: bit0 = any h0 nonzero, bit1 = any c0 nonzero.
__global__ __launch_bounds__(1024) void k_hist(const int* __restrict__ src,
                                               const int* __restrict__ dst,
                                               int* __restrict__ hist,
                                               const float* __restrict__ h0,
                                               const float* __restrict__ c0,
                                               int* __restrict__ flag,
                                               int E, int chunk, int ng, int total4) {
    __shared__ int hS[GW], hD[GW];
    int t = threadIdx.x, b = blockIdx.x;
    for (int i = t; i < ng; i += 1024) { hS[i] = 0; hD[i] = 0; }
    __syncthreads();
    int beg = b * chunk, end = min(E, beg + chunk);
    for (int e = beg + t; e < end; e += 1024) {
        atomicAdd(&hS[src[e] >> GSH], 1);
        atomicAdd(&hD[dst[e] >> GSH], 1);
    }
    // flag scan: grid-stride float4 over h0 and c0 (N*32 divisible by 4)
    bool ah = false, ac = false;
    for (int i = b * 1024 + t; i < total4; i += NB * 1024) {
        float4 a = ((const float4*)h0)[i];
        float4 c = ((const float4*)c0)[i];
        ah |= (a.x != 0.0f) | (a.y != 0.0f) | (a.z != 0.0f) | (a.w != 0.0f);
        ac |= (c.x != 0.0f) | (c.y != 0.0f) | (c.z != 0.0f) | (c.w != 0.0f);
    }
    unsigned long long bh = __ballot(ah);
    unsigned long long bc = __ballot(ac);
    if ((t & 63) == 0) {
        int m = (bh ? 1 : 0) | (bc ? 2 : 0);
        if (m) atomicOr(flag, m);
    }
    __syncthreads();
    for (int i = t; i < ng; i += 1024) {
        hist[(size_t)i * NB + b] = hS[i];               // S bins: [0, ng)
        hist[((size_t)ng + i) * NB + b] = hD[i];        // D bins: [ng, 2ng)
    }
}

// per-bin exclusive scan across the NB blocks (one block per bin)
__global__ __launch_bounds__(256) void k_binscan(const int* __restrict__ hist,
                                                 int* __restrict__ off,
                                                 int* __restrict__ binTot, int ng2) {
    __shared__ int s[256];
    int b2 = blockIdx.x, t = threadIdx.x;
    int v = hist[(size_t)b2 * NB + t];                  // coalesced
    s[t] = v;
    __syncthreads();
    for (int o = 1; o < 256; o <<= 1) {
        int x = (t >= o) ? s[t - o] : 0;
        __syncthreads();
        s[t] += x;
        __syncthreads();
    }
    off[(size_t)t * ng2 + b2] = s[t] - v;               // block-major (scattered)
    if (t == 255) binTot[b2] = s[255];
}

// 2 blocks x 1024: block 0 scans S bin totals, block 1 scans D bin totals.
__global__ __launch_bounds__(1024) void k_binbase(const int* __restrict__ binTot,
                                                  int* __restrict__ baseS, int* __restrict__ baseD,
                                                  int* __restrict__ rowptr,
                                                  int E, int ng, int N) {
    __shared__ int buf[1024];
    int t = threadIdx.x;
    int isD = blockIdx.x;
    int sum = (t < ng) ? binTot[isD * ng + t] : 0;
    buf[t] = sum;
    __syncthreads();
    for (int o = 1; o < 1024; o <<= 1) {
        int v = (t >= o) ? buf[t - o] : 0;
        __syncthreads();
        buf[t] += v;
        __syncthreads();
    }
    int base = buf[t] - sum;                            // exclusive
    int* B = isD ? baseD : baseS;
    if (t < ng) B[t] = base;
    if (t == 0) { B[ng] = E; if (!isD) rowptr[N] = E; }
}

// per-edge scatter into 256-wide groups (both keyings) using LDS cursors.
__global__ __launch_bounds__(1024) void k_scatter(const int* __restrict__ src,
                                                  const int* __restrict__ dst,
                                                  const float* __restrict__ w,
                                                  const int* __restrict__ off,
                                                  const int* __restrict__ baseS,
                                                  const int* __restrict__ baseD,
                                                  int2* __restrict__ tmpS, int2* __restrict__ tmpD,
                                                  int E, int chunk, int ng) {
    __shared__ int cS[GW], cD[GW];
    int t = threadIdx.x, b = blockIdx.x;
    int ng2 = 2 * ng;
    for (int i = t; i < ng; i += 1024) {
        cS[i] = off[(size_t)b * ng2 + i] + baseS[i];          // coalesced
        cD[i] = off[(size_t)b * ng2 + ng + i] + baseD[i];
    }
    __syncthreads();
    int beg = b * chunk, end = min(E, beg + chunk);
    for (int e = beg + t; e < end; e += 1024) {
        int s = src[e], d = dst[e];
        int wb = __float_as_int(w[e]);
        int pS = atomicAdd(&cS[s >> GSH], 1);
        tmpS[pS] = make_int2(s, wb);
        int pD = atomicAdd(&cD[d >> GSH], 1);
        tmpD[pD] = make_int2(s | ((d & (GW - 1)) << 16), wb); // src fits 16 bits
    }
}

// per src-group: LDS float histogram over low 8 bits -> dinv (no global atomics)
__global__ __launch_bounds__(1024) void k_degsum(const int2* __restrict__ tmpS,
                                                 const int* __restrict__ baseS,
                                                 float* __restrict__ dinv, int N) {
    __shared__ float h[GW];
    int g = blockIdx.x, t = threadIdx.x;
    if (t < GW) h[t] = 0.0f;
    __syncthreads();
    int beg = baseS[g], end = baseS[g + 1];
    for (int i = beg + t; i < end; i += 1024) {
        int2 p = tmpS[i];
        atomicAdd(&h[p.x & (GW - 1)], __int_as_float(p.y));
    }
    __syncthreads();
    if (t < GW) {
        int n = (g << GSH) + t;
        if (n < N) { float s = h[t]; dinv[n] = (s > 0.0f) ? rsqrtf(s) : 0.0f; }
    }
}

// per dst-group: low-bits count + scan -> rowptr; then bin edges to exact dst,
// computing nw now that dinv exists. Within-dst order is arbitrary (sum).
__global__ __launch_bounds__(1024) void k_scatter2(const int2* __restrict__ tmpD,
                                                   const int* __restrict__ baseD,
                                                   const float* __restrict__ dinv,
                                                   int* __restrict__ rowptr,
                                                   int2* __restrict__ epair, int N) {
    __shared__ int h[GW], cur[GW];
    int g = blockIdx.x, t = threadIdx.x;
    if (t < GW) h[t] = 0;
    __syncthreads();
    int beg = baseD[g], end = baseD[g + 1];
    for (int i = beg + t; i < end; i += 1024) atomicAdd(&h[(tmpD[i].x >> 16) & (GW - 1)], 1);
    __syncthreads();
    int v = (t < GW) ? h[t] : 0;
    for (int o = 1; o < GW; o <<= 1) {
        int x = (t < GW && t >= o) ? h[t - o] : 0;
        __syncthreads();
        if (t < GW && t >= o) h[t] += x;
        __syncthreads();
    }
    if (t < GW) {
        int excl = h[t] - v;
        int n = (g << GSH) + t;
        if (n < N) rowptr[n] = beg + excl;
        cur[t] = beg + excl;
    }
    __syncthreads();
    for (int i = beg + t; i < end; i += 1024) {
        int2 p = tmpD[i];
        int low = (p.x >> 16) & (GW - 1);
        int s = p.x & 0xFFFF;
        int pos = atomicAdd(&cur[low], 1);
        float nw = -dinv[s] * __int_as_float(p.y) * dinv[(g << GSH) + low];
        epair[pos] = make_int2(s, __float_as_int(nw));
    }
}

// per dst node (32 lanes = 32 feats): accumulate LX (and LH if h0 nonzero)
__global__ __launch_bounds__(256) void k_gather(const int* __restrict__ rowptr,
                                                const int2* __restrict__ epair,
                                                const float* __restrict__ X,
                                                const float* __restrict__ H0,
                                                const int* __restrict__ hflag,
                                                float* __restrict__ LX, float* __restrict__ LH,
                                                int N) {
    int tid = blockIdx.x * 256 + threadIdx.x;
    int n = tid >> 5;
    int f = tid & 31;
    if (n >= N) return;
    int beg = rowptr[n], end = rowptr[n + 1];
    float acc = 0.0f, accH = 0.0f;
    int fl = *hflag;
    if (fl & 1) {
        #pragma unroll 4
        for (int i = beg; i < end; ++i) {
            int2 p = epair[i];
            float w = __int_as_float(p.y);
            acc  += w * X[(p.x << 5) + f];
            accH += w * H0[(p.x << 5) + f];
        }
    } else {
        #pragma unroll 4
        for (int i = beg; i < end; ++i) {
            int2 p = epair[i];
            acc += __int_as_float(p.y) * X[(p.x << 5) + f];
        }
    }
    LX[(n << 5) + f] = acc;
    if (fl & 1) LH[(n << 5) + f] = accH;   // LH is logically 0 otherwise; never read then
}

// Per (node-group g of NPT nodes, out-feature j): fused LSTM cell (no head).
// Fast path (h0==0 && c0==0, detected at runtime): F-gate dead (C = I*T),
// h/lh terms are exact zero-adds -> 3 gates x 2 input types. Bit-identical.
__global__ __launch_bounds__(256) void k_gates(
    const float* __restrict__ X, const float* __restrict__ LX,
    const float* __restrict__ H0, const float* __restrict__ LH,
    const float* __restrict__ C0,
    const float* __restrict__ Wx, const float* __restrict__ bx,
    const float* __restrict__ Wh, const float* __restrict__ bh,
    const float* __restrict__ wc, const float* __restrict__ b,
    const int* __restrict__ flag,
    float* __restrict__ outH, float* __restrict__ outC, int N) {
    int tid = blockIdx.x * 256 + threadIdx.x;
    int g = tid >> 5;           // node group
    int j = tid & 31;           // output feature
    int n0 = g * NPT;
    if (n0 >= N) return;
    int cnt = min(NPT, N - n0);
    int f2 = *flag;

    if (f2 == 0) {
        // ---- fast path: h0 == 0 and c0 == 0 ----
        float xk[NPT], lxk[NPT];
        #pragma unroll
        for (int i = 0; i < NPT; ++i) { xk[i] = 0.0f; lxk[i] = 0.0f; }
        for (int i = 0; i < cnt; ++i) {
            int base = (n0 + i) << 5;
            xk[i]  = X[base + j];
            lxk[i] = LX[base + j];
        }
        float p0[NPT], p2[NPT], p3[NPT];
        float b0 = bx[0 * HID + j] + bh[0 * HID + j] + b[0 * HID + j];
        float b2 = bx[2 * HID + j] + bh[2 * HID + j] + b[2 * HID + j];
        float b3 = bx[3 * HID + j] + bh[3 * HID + j] + b[3 * HID + j];
        #pragma unroll
        for (int i = 0; i < NPT; ++i) { p0[i] = b0; p2[i] = b2; p3[i] = b3; }

        #pragma unroll 4
        for (int k = 0; k < HID; ++k) {
            int row = k * HID + j;
            float w00 = Wx[row],            w01 = Wx[1024 + row];
            float w20 = Wx[2 * 2048 + row], w21 = Wx[2 * 2048 + 1024 + row];
            float w30 = Wx[3 * 2048 + row], w31 = Wx[3 * 2048 + 1024 + row];
            #pragma unroll
            for (int i = 0; i < NPT; ++i) {
                float xv  = __shfl(xk[i],  k, 32);
                float lxv = __shfl(lxk[i], k, 32);
                p0[i] += xv * w00 + lxv * w01;
                p2[i] += xv * w20 + lxv * w21;
                p3[i] += xv * w30 + lxv * w31;
            }
        }

        float wc2 = wc[2 * HID + j];
        for (int i = 0; i < cnt; ++i) {
            int base = (n0 + i) << 5;
            float I = sigmoidf_(p0[i]);
            float T = tanhf(p2[i]);
            float C = I * T;
            float O = sigmoidf_(p3[i] + wc2 * C);
            outH[base + j] = O * tanhf(C);
            outC[base + j] = C;
        }
        return;
    }

    // ---- general path ----
    float xk[NPT], lxk[NPT], hk[NPT], lhk[NPT];
    #pragma unroll
    for (int i = 0; i < NPT; ++i) { xk[i] = 0.0f; lxk[i] = 0.0f; hk[i] = 0.0f; lhk[i] = 0.0f; }
    for (int i = 0; i < cnt; ++i) {
        int base = (n0 + i) << 5;
        xk[i]  = X[base + j];
        lxk[i] = LX[base + j];
        hk[i]  = H0[base + j];
        lhk[i] = (f2 & 1) ? LH[base + j] : 0.0f;   // LH only valid if h0 nonzero
    }

    float pre[4][NPT];
    #pragma unroll
    for (int gt = 0; gt < 4; ++gt) {
        float bb = bx[gt * HID + j] + bh[gt * HID + j] + b[gt * HID + j];
        #pragma unroll
        for (int i = 0; i < NPT; ++i) pre[gt][i] = bb;
    }

    #pragma unroll 2
    for (int k = 0; k < HID; ++k) {
        float w0[4], w1[4], w2[4], w3[4];
        int row = k * HID + j;
        #pragma unroll
        for (int gt = 0; gt < 4; ++gt) {
            w0[gt] = Wx[gt * 2048 + row];
            w1[gt] = Wx[gt * 2048 + 1024 + row];
            w2[gt] = Wh[gt * 2048 + row];
            w3[gt] = Wh[gt * 2048 + 1024 + row];
        }
        #pragma unroll
        for (int i = 0; i < NPT; ++i) {
            float xv  = __shfl(xk[i],  k, 32);
            float lxv = __shfl(lxk[i], k, 32);
            float hv  = __shfl(hk[i],  k, 32);
            float lhv = __shfl(lhk[i], k, 32);
            #pragma unroll
            for (int gt = 0; gt < 4; ++gt)
                pre[gt][i] += xv * w0[gt] + lxv * w1[gt] + hv * w2[gt] + lhv * w3[gt];
        }
    }

    float wc0 = wc[0 * HID + j], wc1 = wc[1 * HID + j], wc2 = wc[2 * HID + j];
    for (int i = 0; i < cnt; ++i) {
        int base = (n0 + i) << 5;
        float c0v = C0[base + j];
        float I  = sigmoidf_(pre[0][i] + wc0 * c0v);
        float Fg = sigmoidf_(pre[1][i] + wc1 * c0v);
        float T  = tanhf(pre[2][i]);
        float C  = Fg * c0v + I * T;
        float O  = sigmoidf_(pre[3][i] + wc2 * C);
        float H  = O * tanhf(C);
        outH[base + j] = H;
        outC[base + j] = C;
    }
}

// h[n,t] = b_lin[t] + sum_k relu(H[n,k]) * W_lin[k,t]
__global__ void k_head(const float* __restrict__ H, const float* __restrict__ Wl,
                       const float* __restrict__ bl, float* __restrict__ hout, int N) {
    int tid = blockIdx.x * 256 + threadIdx.x;
    int n = tid / HOR;
    int t = tid - n * HOR;
    if (n >= N) return;
    float acc = bl[t];
    #pragma unroll
    for (int k = 0; k < HID; ++k) {
        float v = H[(n << 5) + k];
        acc += fmaxf(v, 0.0f) * Wl[k * HOR + t];
    }
    hout[n * HOR + t] = acc;
}

extern "C" void kernel_launch(void* const* d_in, const int* in_sizes, int n_in,
                              void* d_out, int out_size, void* d_ws, size_t ws_size,
                              hipStream_t stream) {
    const float* x  = (const float*)d_in[0];
    const int*   ei = (const int*)d_in[1];
    const float* ew = (const float*)d_in[2];
    const float* Wx = (const float*)d_in[3];
    const float* bx = (const float*)d_in[4];
    const float* Wh = (const float*)d_in[5];
    const float* bh = (const float*)d_in[6];
    const float* wc = (const float*)d_in[7];
    const float* b  = (const float*)d_in[8];
    const float* Wl = (const float*)d_in[9];
    const float* bl = (const float*)d_in[10];
    const float* h0 = (const float*)d_in[11];
    const float* c0 = (const float*)d_in[12];

    int N = in_sizes[0] / HID;      // x is (N,1,32)
    int E = in_sizes[2];            // edge_weight is (E,)
    const int* src = ei;
    const int* dst = ei + E;

    int ng = (N + GW - 1) >> GSH;   // 196 groups (requires N <= 65536)
    int ng2 = 2 * ng;
    int chunk = (E + NB - 1) / NB;  // edges per hist/scatter block

    // workspace (4-byte units):
    // [tmpD 2E] [tmpS 2E (aliased by epair)] [LX N*32] [LH N*32] [rowptr N+1]
    // [hist ng2*NB] [off ng2*NB] [binTot 2048] [baseS ng+1] [baseD ng+1] [dinv N] [flag 1]
    // tmpS is dead after k_degsum, so k_scatter2 may overwrite it with epair.
    int* wsi = (int*)d_ws;
    int2*  tmpD   = (int2*)wsi;
    int2*  tmpS   = (int2*)(wsi + 2 * (size_t)E);
    int2*  epair  = tmpS;                                // alias (see above)
    float* LX     = (float*)(wsi + 4 * (size_t)E);
    float* LH     = LX + (size_t)N * HID;
    int*   rowptr = (int*)(LH + (size_t)N * HID);
    int*   hist   = rowptr + (N + 1);
    int*   off    = hist + (size_t)ng2 * NB;
    int*   binTot = off + (size_t)ng2 * NB;
    int*   baseS  = binTot + 2048;
    int*   baseD  = baseS + (ng + 1);
    float* dinv   = (float*)(baseD + (ng + 1));
    int*   flag   = (int*)(dinv + N);

    float* hOut = (float*)d_out;            // (N,12)
    float* HOut = hOut + (size_t)N * HOR;   // (N,32)
    float* COut = HOut + (size_t)N * HID;   // (N,32)

    hipMemsetAsync(flag, 0, sizeof(int), stream);

    k_hist<<<NB, 1024, 0, stream>>>(src, dst, hist, h0, c0, flag, E, chunk, ng, (N * HID) >> 2);
    k_binscan<<<ng2, 256, 0, stream>>>(hist, off, binTot, ng2);
    k_binbase<<<2, 1024, 0, stream>>>(binTot, baseS, baseD, rowptr, E, ng, N);
    k_scatter<<<NB, 1024, 0, stream>>>(src, dst, ew, off, baseS, baseD, tmpS, tmpD, E, chunk, ng);
    k_degsum<<<ng, 1024, 0, stream>>>(tmpS, baseS, dinv, N);
    k_scatter2<<<ng, 1024, 0, stream>>>(tmpD, baseD, dinv, rowptr, epair, N);

    k_gather<<<(N * HID + 255) / 256, 256, 0, stream>>>(rowptr, epair, x, h0, flag, LX, LH, N);

    int gThreads = ((N + NPT - 1) / NPT) * 32;
    k_gates<<<(gThreads + 255) / 256, 256, 0, stream>>>(x, LX, h0, LH, c0,
                                                        Wx, bx, Wh, bh, wc, b, flag,
                                                        HOut, COut, N);

    k_head<<<(N * HOR + 255) / 256, 256, 0, stream>>>(HOut, Wl, bl, hOut, N);
}

// Round 14
// 241.109 us; speedup vs baseline: 6.9973x; 1.0100x over previous
//
#include <hip/hip_runtime.h>
#include <math.h>

#define HID 32
#define HOR 12
#define NB  256   // first-level blocks; k_binscan's 256 threads own one block each
#define GSH 8     // group shift: 256 nodes per group (ng=196 <= 256)
#define GW  256   // group width
#define NPT 4     // nodes per thread in k_gates
#define TILE 4096 // edges per staged-scatter tile
#define SBINS 256 // padded bin count for the staged scatter (ng <= 256)

__device__ __forceinline__ float sigmoidf_(float x) { return 1.0f / (1.0f + expf(-x)); }

// ---------------------------------------------------------------------------
// Round-13 champion (243.5 us) with ONE change: k_scatter is tile-staged.
// Each 4096-edge tile is ranked by group with LDS atomics, scanned, sorted
// into a 32KB LDS staging buffer, then flushed in consecutive full-line runs
// (one group's entries are contiguous). Kills the partial-line write
// amplification (r5: 85MB written vs 25.6MB ideal). Two passes (S keying,
// then D keying) halve the open-stream count. tmpD.x packs s|dlow<<16|g<<24
// (g<=195 fits 8 bits); downstream consumers mask, so no other change.
// ---------------------------------------------------------------------------

// per-block histograms of src>>8 and dst>>8, written bin-major.
// Also computes flag: bit0 = any h0 nonzero, bit1 = any c0 nonzero.
__global__ __launch_bounds__(1024) void k_hist(const int* __restrict__ src,
                                               const int* __restrict__ dst,
                                               int* __restrict__ hist,
                                               const float* __restrict__ h0,
                                               const float* __restrict__ c0,
                                               int* __restrict__ flag,
                                               int E, int chunk, int ng, int total4) {
    __shared__ int hS[GW], hD[GW];
    int t = threadIdx.x, b = blockIdx.x;
    for (int i = t; i < ng; i += 1024) { hS[i] = 0; hD[i] = 0; }
    __syncthreads();
    int beg = b * chunk, end = min(E, beg + chunk);
    for (int e = beg + t; e < end; e += 1024) {
        atomicAdd(&hS[src[e] >> GSH], 1);
        atomicAdd(&hD[dst[e] >> GSH], 1);
    }
    // flag scan: grid-stride float4 over h0 and c0 (N*32 divisible by 4)
    bool ah = false, ac = false;
    for (int i = b * 1024 + t; i < total4; i += NB * 1024) {
        float4 a = ((const float4*)h0)[i];
        float4 c = ((const float4*)c0)[i];
        ah |= (a.x != 0.0f) | (a.y != 0.0f) | (a.z != 0.0f) | (a.w != 0.0f);
        ac |= (c.x != 0.0f) | (c.y != 0.0f) | (c.z != 0.0f) | (c.w != 0.0f);
    }
    unsigned long long bh = __ballot(ah);
    unsigned long long bc = __ballot(ac);
    if ((t & 63) == 0) {
        int m = (bh ? 1 : 0) | (bc ? 2 : 0);
        if (m) atomicOr(flag, m);
    }
    __syncthreads();
    for (int i = t; i < ng; i += 1024) {
        hist[(size_t)i * NB + b] = hS[i];               // S bins: [0, ng)
        hist[((size_t)ng + i) * NB + b] = hD[i];        // D bins: [ng, 2ng)
    }
}

// per-bin exclusive scan across the NB blocks (one block per bin)
__global__ __launch_bounds__(256) void k_binscan(const int* __restrict__ hist,
                                                 int* __restrict__ off,
                                                 int* __restrict__ binTot, int ng2) {
    __shared__ int s[256];
    int b2 = blockIdx.x, t = threadIdx.x;
    int v = hist[(size_t)b2 * NB + t];                  // coalesced
    s[t] = v;
    __syncthreads();
    for (int o = 1; o < 256; o <<= 1) {
        int x = (t >= o) ? s[t - o] : 0;
        __syncthreads();
        s[t] += x;
        __syncthreads();
    }
    off[(size_t)t * ng2 + b2] = s[t] - v;               // block-major (scattered)
    if (t == 255) binTot[b2] = s[255];
}

// 2 blocks x 1024: block 0 scans S bin totals, block 1 scans D bin totals.
__global__ __launch_bounds__(1024) void k_binbase(const int* __restrict__ binTot,
                                                  int* __restrict__ baseS, int* __restrict__ baseD,
                                                  int* __restrict__ rowptr,
                                                  int E, int ng, int N) {
    __shared__ int buf[1024];
    int t = threadIdx.x;
    int isD = blockIdx.x;
    int sum = (t < ng) ? binTot[isD * ng + t] : 0;
    buf[t] = sum;
    __syncthreads();
    for (int o = 1; o < 1024; o <<= 1) {
        int v = (t >= o) ? buf[t - o] : 0;
        __syncthreads();
        buf[t] += v;
        __syncthreads();
    }
    int base = buf[t] - sum;                            // exclusive
    int* B = isD ? baseD : baseS;
    if (t < ng) B[t] = base;
    if (t == 0) { B[ng] = E; if (!isD) rowptr[N] = E; }
}

// tile-staged scatter: pass 0 = S keying -> tmpS, pass 1 = D keying -> tmpD.
// Per tile: rank (LDS atomics) -> scan -> sort into LDS -> coalesced flush.
__global__ __launch_bounds__(1024) void k_scatter(const int* __restrict__ src,
                                                  const int* __restrict__ dst,
                                                  const float* __restrict__ w,
                                                  const int* __restrict__ off,
                                                  const int* __restrict__ baseS,
                                                  const int* __restrict__ baseD,
                                                  int2* __restrict__ tmpS, int2* __restrict__ tmpD,
                                                  int E, int chunk, int ng) {
    __shared__ int2 stage[TILE];      // 32 KB
    __shared__ int cnt[SBINS];        // 1 KB
    __shared__ int gcur[SBINS];       // 1 KB
    int t = threadIdx.x, b = blockIdx.x;
    int beg = b * chunk, end = min(E, beg + chunk);
    int ng2 = 2 * ng;

    for (int pass = 0; pass < 2; ++pass) {
        if (t < ng) gcur[t] = (pass == 0) ? off[(size_t)b * ng2 + t] + baseS[t]
                                          : off[(size_t)b * ng2 + ng + t] + baseD[t];
        __syncthreads();

        for (int tb = beg; tb < end; tb += TILE) {
            int tcount = min(TILE, end - tb);
            if (t < SBINS) cnt[t] = 0;
            __syncthreads();

            // load + rank
            int g_[4], r_[4];
            int2 p_[4];
            #pragma unroll
            for (int u = 0; u < 4; ++u) {
                int li = u * 1024 + t;
                g_[u] = -1;
                if (li < tcount) {
                    int e = tb + li;
                    int s = src[e];
                    int wb = __float_as_int(w[e]);
                    int g;
                    if (pass == 0) { g = s >> GSH; p_[u] = make_int2(s, wb); }
                    else {
                        int d = dst[e]; g = d >> GSH;
                        p_[u] = make_int2(s | ((d & (GW - 1)) << 16) | (g << 24), wb);
                    }
                    g_[u] = g;
                    r_[u] = atomicAdd(&cnt[g], 1);
                }
            }
            __syncthreads();

            // exclusive scan of cnt over SBINS bins (threads t < SBINS)
            int c = (t < SBINS) ? cnt[t] : 0;
            for (int o = 1; o < SBINS; o <<= 1) {
                int v = (t < SBINS && t >= o) ? cnt[t - o] : 0;
                __syncthreads();
                if (t < SBINS && t >= o) cnt[t] += v;
                __syncthreads();
            }
            if (t < SBINS) cnt[t] -= c;                 // exclusive
            __syncthreads();

            // place into staging (tile now sorted by group)
            #pragma unroll
            for (int u = 0; u < 4; ++u)
                if (g_[u] >= 0) stage[cnt[g_[u]] + r_[u]] = p_[u];
            __syncthreads();

            // coalesced flush: consecutive i in a group -> consecutive addrs
            int2* out = (pass == 0) ? tmpS : tmpD;
            for (int i = t; i < tcount; i += 1024) {
                int2 p = stage[i];
                int g = (pass == 0) ? (p.x >> GSH) : ((p.x >> 24) & 255);
                out[gcur[g] + (i - cnt[g])] = p;
            }
            __syncthreads();

            if (t < SBINS) gcur[t] += c;
            __syncthreads();
        }
        __syncthreads();
    }
}

// per src-group: LDS float histogram over low 8 bits -> dinv (no global atomics)
__global__ __launch_bounds__(1024) void k_degsum(const int2* __restrict__ tmpS,
                                                 const int* __restrict__ baseS,
                                                 float* __restrict__ dinv, int N) {
    __shared__ float h[GW];
    int g = blockIdx.x, t = threadIdx.x;
    if (t < GW) h[t] = 0.0f;
    __syncthreads();
    int beg = baseS[g], end = baseS[g + 1];
    for (int i = beg + t; i < end; i += 1024) {
        int2 p = tmpS[i];
        atomicAdd(&h[p.x & (GW - 1)], __int_as_float(p.y));
    }
    __syncthreads();
    if (t < GW) {
        int n = (g << GSH) + t;
        if (n < N) { float s = h[t]; dinv[n] = (s > 0.0f) ? rsqrtf(s) : 0.0f; }
    }
}

// per dst-group: low-bits count + scan -> rowptr; then bin edges to exact dst,
// computing nw now that dinv exists. Within-dst order is arbitrary (sum).
__global__ __launch_bounds__(1024) void k_scatter2(const int2* __restrict__ tmpD,
                                                   const int* __restrict__ baseD,
                                                   const float* __restrict__ dinv,
                                                   int* __restrict__ rowptr,
                                                   int2* __restrict__ epair, int N) {
    __shared__ int h[GW], cur[GW];
    int g = blockIdx.x, t = threadIdx.x;
    if (t < GW) h[t] = 0;
    __syncthreads();
    int beg = baseD[g], end = baseD[g + 1];
    for (int i = beg + t; i < end; i += 1024) atomicAdd(&h[(tmpD[i].x >> 16) & (GW - 1)], 1);
    __syncthreads();
    int v = (t < GW) ? h[t] : 0;
    for (int o = 1; o < GW; o <<= 1) {
        int x = (t < GW && t >= o) ? h[t - o] : 0;
        __syncthreads();
        if (t < GW && t >= o) h[t] += x;
        __syncthreads();
    }
    if (t < GW) {
        int excl = h[t] - v;
        int n = (g << GSH) + t;
        if (n < N) rowptr[n] = beg + excl;
        cur[t] = beg + excl;
    }
    __syncthreads();
    for (int i = beg + t; i < end; i += 1024) {
        int2 p = tmpD[i];
        int low = (p.x >> 16) & (GW - 1);
        int s = p.x & 0xFFFF;
        int pos = atomicAdd(&cur[low], 1);
        float nw = -dinv[s] * __int_as_float(p.y) * dinv[(g << GSH) + low];
        epair[pos] = make_int2(s, __float_as_int(nw));
    }
}

// per dst node (32 lanes = 32 feats): accumulate LX (and LH if h0 nonzero)
__global__ __launch_bounds__(256) void k_gather(const int* __restrict__ rowptr,
                                                const int2* __restrict__ epair,
                                                const float* __restrict__ X,
                                                const float* __restrict__ H0,
                                                const int* __restrict__ hflag,
                                                float* __restrict__ LX, float* __restrict__ LH,
                                                int N) {
    int tid = blockIdx.x * 256 + threadIdx.x;
    int n = tid >> 5;
    int f = tid & 31;
    if (n >= N) return;
    int beg = rowptr[n], end = rowptr[n + 1];
    float acc = 0.0f, accH = 0.0f;
    int fl = *hflag;
    if (fl & 1) {
        #pragma unroll 4
        for (int i = beg; i < end; ++i) {
            int2 p = epair[i];
            float w = __int_as_float(p.y);
            acc  += w * X[(p.x << 5) + f];
            accH += w * H0[(p.x << 5) + f];
        }
    } else {
        #pragma unroll 4
        for (int i = beg; i < end; ++i) {
            int2 p = epair[i];
            acc += __int_as_float(p.y) * X[(p.x << 5) + f];
        }
    }
    LX[(n << 5) + f] = acc;
    if (fl & 1) LH[(n << 5) + f] = accH;   // LH is logically 0 otherwise; never read then
}

// Per (node-group g of NPT nodes, out-feature j): fused LSTM cell (no head).
// Fast path (h0==0 && c0==0, detected at runtime): F-gate dead (C = I*T),
// h/lh terms are exact zero-adds -> 3 gates x 2 input types. Bit-identical.
__global__ __launch_bounds__(256) void k_gates(
    const float* __restrict__ X, const float* __restrict__ LX,
    const float* __restrict__ H0, const float* __restrict__ LH,
    const float* __restrict__ C0,
    const float* __restrict__ Wx, const float* __restrict__ bx,
    const float* __restrict__ Wh, const float* __restrict__ bh,
    const float* __restrict__ wc, const float* __restrict__ b,
    const int* __restrict__ flag,
    float* __restrict__ outH, float* __restrict__ outC, int N) {
    int tid = blockIdx.x * 256 + threadIdx.x;
    int g = tid >> 5;           // node group
    int j = tid & 31;           // output feature
    int n0 = g * NPT;
    if (n0 >= N) return;
    int cnt = min(NPT, N - n0);
    int f2 = *flag;

    if (f2 == 0) {
        // ---- fast path: h0 == 0 and c0 == 0 ----
        float xk[NPT], lxk[NPT];
        #pragma unroll
        for (int i = 0; i < NPT; ++i) { xk[i] = 0.0f; lxk[i] = 0.0f; }
        for (int i = 0; i < cnt; ++i) {
            int base = (n0 + i) << 5;
            xk[i]  = X[base + j];
            lxk[i] = LX[base + j];
        }
        float p0[NPT], p2[NPT], p3[NPT];
        float b0 = bx[0 * HID + j] + bh[0 * HID + j] + b[0 * HID + j];
        float b2 = bx[2 * HID + j] + bh[2 * HID + j] + b[2 * HID + j];
        float b3 = bx[3 * HID + j] + bh[3 * HID + j] + b[3 * HID + j];
        #pragma unroll
        for (int i = 0; i < NPT; ++i) { p0[i] = b0; p2[i] = b2; p3[i] = b3; }

        #pragma unroll 4
        for (int k = 0; k < HID; ++k) {
            int row = k * HID + j;
            float w00 = Wx[row],            w01 = Wx[1024 + row];
            float w20 = Wx[2 * 2048 + row], w21 = Wx[2 * 2048 + 1024 + row];
            float w30 = Wx[3 * 2048 + row], w31 = Wx[3 * 2048 + 1024 + row];
            #pragma unroll
            for (int i = 0; i < NPT; ++i) {
                float xv  = __shfl(xk[i],  k, 32);
                float lxv = __shfl(lxk[i], k, 32);
                p0[i] += xv * w00 + lxv * w01;
                p2[i] += xv * w20 + lxv * w21;
                p3[i] += xv * w30 + lxv * w31;
            }
        }

        float wc2 = wc[2 * HID + j];
        for (int i = 0; i < cnt; ++i) {
            int base = (n0 + i) << 5;
            float I = sigmoidf_(p0[i]);
            float T = tanhf(p2[i]);
            float C = I * T;
            float O = sigmoidf_(p3[i] + wc2 * C);
            outH[base + j] = O * tanhf(C);
            outC[base + j] = C;
        }
        return;
    }

    // ---- general path ----
    float xk[NPT], lxk[NPT], hk[NPT], lhk[NPT];
    #pragma unroll
    for (int i = 0; i < NPT; ++i) { xk[i] = 0.0f; lxk[i] = 0.0f; hk[i] = 0.0f; lhk[i] = 0.0f; }
    for (int i = 0; i < cnt; ++i) {
        int base = (n0 + i) << 5;
        xk[i]  = X[base + j];
        lxk[i] = LX[base + j];
        hk[i]  = H0[base + j];
        lhk[i] = (f2 & 1) ? LH[base + j] : 0.0f;   // LH only valid if h0 nonzero
    }

    float pre[4][NPT];
    #pragma unroll
    for (int gt = 0; gt < 4; ++gt) {
        float bb = bx[gt * HID + j] + bh[gt * HID + j] + b[gt * HID + j];
        #pragma unroll
        for (int i = 0; i < NPT; ++i) pre[gt][i] = bb;
    }

    #pragma unroll 2
    for (int k = 0; k < HID; ++k) {
        float w0[4], w1[4], w2[4], w3[4];
        int row = k * HID + j;
        #pragma unroll
        for (int gt = 0; gt < 4; ++gt) {
            w0[gt] = Wx[gt * 2048 + row];
            w1[gt] = Wx[gt * 2048 + 1024 + row];
            w2[gt] = Wh[gt * 2048 + row];
            w3[gt] = Wh[gt * 2048 + 1024 + row];
        }
        #pragma unroll
        for (int i = 0; i < NPT; ++i) {
            float xv  = __shfl(xk[i],  k, 32);
            float lxv = __shfl(lxk[i], k, 32);
            float hv  = __shfl(hk[i],  k, 32);
            float lhv = __shfl(lhk[i], k, 32);
            #pragma unroll
            for (int gt = 0; gt < 4; ++gt)
                pre[gt][i] += xv * w0[gt] + lxv * w1[gt] + hv * w2[gt] + lhv * w3[gt];
        }
    }

    float wc0 = wc[0 * HID + j], wc1 = wc[1 * HID + j], wc2 = wc[2 * HID + j];
    for (int i = 0; i < cnt; ++i) {
        int base = (n0 + i) << 5;
        float c0v = C0[base + j];
        float I  = sigmoidf_(pre[0][i] + wc0 * c0v);
        float Fg = sigmoidf_(pre[1][i] + wc1 * c0v);
        float T  = tanhf(pre[2][i]);
        float C  = Fg * c0v + I * T;
        float O  = sigmoidf_(pre[3][i] + wc2 * C);
        float H  = O * tanhf(C);
        outH[base + j] = H;
        outC[base + j] = C;
    }
}

// h[n,t] = b_lin[t] + sum_k relu(H[n,k]) * W_lin[k,t]
__global__ void k_head(const float* __restrict__ H, const float* __restrict__ Wl,
                       const float* __restrict__ bl, float* __restrict__ hout, int N) {
    int tid = blockIdx.x * 256 + threadIdx.x;
    int n = tid / HOR;
    int t = tid - n * HOR;
    if (n >= N) return;
    float acc = bl[t];
    #pragma unroll
    for (int k = 0; k < HID; ++k) {
        float v = H[(n << 5) + k];
        acc += fmaxf(v, 0.0f) * Wl[k * HOR + t];
    }
    hout[n * HOR + t] = acc;
}

extern "C" void kernel_launch(void* const* d_in, const int* in_sizes, int n_in,
                              void* d_out, int out_size, void* d_ws, size_t ws_size,
                              hipStream_t stream) {
    const float* x  = (const float*)d_in[0];
    const int*   ei = (const int*)d_in[1];
    const float* ew = (const float*)d_in[2];
    const float* Wx = (const float*)d_in[3];
    const float* bx = (const float*)d_in[4];
    const float* Wh = (const float*)d_in[5];
    const float* bh = (const float*)d_in[6];
    const float* wc = (const float*)d_in[7];
    const float* b  = (const float*)d_in[8];
    const float* Wl = (const float*)d_in[9];
    const float* bl = (const float*)d_in[10];
    const float* h0 = (const float*)d_in[11];
    const float* c0 = (const float*)d_in[12];

    int N = in_sizes[0] / HID;      // x is (N,1,32)
    int E = in_sizes[2];            // edge_weight is (E,)
    const int* src = ei;
    const int* dst = ei + E;

    int ng = (N + GW - 1) >> GSH;   // 196 groups (requires N <= 65536)
    int ng2 = 2 * ng;
    int chunk = (E + NB - 1) / NB;  // edges per hist/scatter block

    // workspace (4-byte units):
    // [tmpD 2E] [tmpS 2E (aliased by epair)] [LX N*32] [LH N*32] [rowptr N+1]
    // [hist ng2*NB] [off ng2*NB] [binTot 2048] [baseS ng+1] [baseD ng+1] [dinv N] [flag 1]
    // tmpS is dead after k_degsum, so k_scatter2 may overwrite it with epair.
    int* wsi = (int*)d_ws;
    int2*  tmpD   = (int2*)wsi;
    int2*  tmpS   = (int2*)(wsi + 2 * (size_t)E);
    int2*  epair  = tmpS;                                // alias (see above)
    float* LX     = (float*)(wsi + 4 * (size_t)E);
    float* LH     = LX + (size_t)N * HID;
    int*   rowptr = (int*)(LH + (size_t)N * HID);
    int*   hist   = rowptr + (N + 1);
    int*   off    = hist + (size_t)ng2 * NB;
    int*   binTot = off + (size_t)ng2 * NB;
    int*   baseS  = binTot + 2048;
    int*   baseD  = baseS + (ng + 1);
    float* dinv   = (float*)(baseD + (ng + 1));
    int*   flag   = (int*)(dinv + N);

    float* hOut = (float*)d_out;            // (N,12)
    float* HOut = hOut + (size_t)N * HOR;   // (N,32)
    float* COut = HOut + (size_t)N * HID;   // (N,32)

    hipMemsetAsync(flag, 0, sizeof(int), stream);

    k_hist<<<NB, 1024, 0, stream>>>(src, dst, hist, h0, c0, flag, E, chunk, ng, (N * HID) >> 2);
    k_binscan<<<ng2, 256, 0, stream>>>(hist, off, binTot, ng2);
    k_binbase<<<2, 1024, 0, stream>>>(binTot, baseS, baseD, rowptr, E, ng, N);
    k_scatter<<<NB, 1024, 0, stream>>>(src, dst, ew, off, baseS, baseD, tmpS, tmpD, E, chunk, ng);
    k_degsum<<<ng, 1024, 0, stream>>>(tmpS, baseS, dinv, N);
    k_scatter2<<<ng, 1024, 0, stream>>>(tmpD, baseD, dinv, rowptr, epair, N);

    k_gather<<<(N * HID + 255) / 256, 256, 0, stream>>>(rowptr, epair, x, h0, flag, LX, LH, N);

    int gThreads = ((N + NPT - 1) / NPT) * 32;
    k_gates<<<(gThreads + 255) / 256, 256, 0, stream>>>(x, LX, h0, LH, c0,
                                                        Wx, bx, Wh, bh, wc, b, flag,
                                                        HOut, COut, N);

    k_head<<<(N * HOR + 255) / 256, 256, 0, stream>>>(HOut, Wl, bl, hOut, N);
}